// Round 1
// baseline (9036.972 us; speedup 1.0000x reference)
//
#include <hip/hip_runtime.h>
#include <hip/hip_bf16.h>
#include <cmath>

#define HH 768
#define WW 768
#define HWSZ (768*768)

// ---------------- backbone: conv3x3 (3->32) + bias + relu, store bf16 ----------------
__global__ __launch_bounds__(256) void backbone_kernel(
    const float* __restrict__ x, const float* __restrict__ w,
    const float* __restrict__ bias, __hip_bfloat16* __restrict__ feats)
{
  int p = blockIdx.x * 256 + threadIdx.x;          // 0 .. 2*768*768-1
  int bb  = p / HWSZ;
  int rem = p - bb * HWSZ;
  int y   = rem / WW;
  int xx  = rem - y * WW;
  const float* xb = x + (size_t)bb * 3 * HWSZ;

  float v[3][3][3];
  #pragma unroll
  for (int c = 0; c < 3; c++)
    #pragma unroll
    for (int dy = 0; dy < 3; dy++)
      #pragma unroll
      for (int dx = 0; dx < 3; dx++) {
        int yy = y + dy - 1, xq = xx + dx - 1;
        v[c][dy][dx] = (yy >= 0 && yy < HH && xq >= 0 && xq < WW)
                         ? xb[(size_t)c * HWSZ + yy * WW + xq] : 0.f;
      }

  __hip_bfloat16* fb = feats + (size_t)bb * 32 * HWSZ;
  #pragma unroll
  for (int o = 0; o < 32; o++) {
    float acc = bias[o];                           // uniform -> s_load
    #pragma unroll
    for (int c = 0; c < 3; c++)
      #pragma unroll
      for (int dy = 0; dy < 3; dy++)
        #pragma unroll
        for (int dx = 0; dx < 3; dx++)
          acc = fmaf(w[((o * 3 + c) * 3 + dy) * 3 + dx], v[c][dy][dx], acc);
    fb[(size_t)o * HWSZ + rem] = __float2bfloat16(fmaxf(acc, 0.f));
  }
}

// ---------------- head: conv KxK (32->32) -> scale/shift -> relu -> conv1x1 ----------------
template <int K, int COUT, bool DO_TANH>
__global__ __launch_bounds__(256) void head_kernel(
    const __hip_bfloat16* __restrict__ feats,
    const float* __restrict__ w1, const float* __restrict__ b1,
    const float* __restrict__ s,  const float* __restrict__ t,
    const float* __restrict__ w2, const float* __restrict__ b2,
    float* __restrict__ out)
{
  constexpr int PAD = K / 2;
  constexpr int TW  = 16 + 2 * PAD;                // tile width with halo
  __shared__ float tile[TW * TW];

  int bx = blockIdx.x % 48;
  int by = (blockIdx.x / 48) % 48;
  int bb = blockIdx.x / (48 * 48);
  int tx = threadIdx.x & 15, ty = threadIdx.x >> 4;
  int x0 = bx * 16 - PAD, y0 = by * 16 - PAD;

  const __hip_bfloat16* fb = feats + (size_t)bb * 32 * HWSZ;

  float mid[32];
  #pragma unroll
  for (int o = 0; o < 32; o++) mid[o] = b1[o];     // uniform -> s_load

  for (int c = 0; c < 32; c++) {
    __syncthreads();                               // protect previous iter reads
    for (int i = threadIdx.x; i < TW * TW; i += 256) {
      int yy = y0 + i / TW, xq = x0 + i % TW;
      float v = 0.f;
      if (yy >= 0 && yy < HH && xq >= 0 && xq < WW)
        v = __bfloat162float(fb[(size_t)c * HWSZ + yy * WW + xq]);
      tile[i] = v;
    }
    __syncthreads();

    const float* wc = w1 + c * K * K;              // + o*32*K*K, all-uniform addresses
    #pragma unroll
    for (int ky = 0; ky < K; ky++) {
      float v[K];
      #pragma unroll
      for (int kx = 0; kx < K; kx++) v[kx] = tile[(ty + ky) * TW + tx + kx];
      #pragma unroll
      for (int o = 0; o < 32; o++) {
        const float* wr = wc + (size_t)o * 32 * K * K + ky * K;
        #pragma unroll
        for (int kx = 0; kx < K; kx++) mid[o] = fmaf(wr[kx], v[kx], mid[o]);
      }
    }
  }

  // folded BN + relu
  #pragma unroll
  for (int o = 0; o < 32; o++)
    mid[o] = fmaxf(fmaf(mid[o], s[o], t[o]), 0.f);

  int ox = bx * 16 + tx, oy = by * 16 + ty;
  size_t pix = (size_t)oy * WW + ox;
  float* ob = out + (size_t)bb * COUT * HWSZ;
  #pragma unroll
  for (int oc = 0; oc < COUT; oc++) {
    float acc = b2[oc];
    #pragma unroll
    for (int o = 0; o < 32; o++) acc = fmaf(w2[oc * 32 + o], mid[o], acc);
    if (DO_TANH) acc = tanhf(acc) * 3.0f;
    ob[(size_t)oc * HWSZ + pix] = acc;
  }
}

extern "C" void kernel_launch(void* const* d_in, const int* in_sizes, int n_in,
                              void* d_out, int out_size, void* d_ws, size_t ws_size,
                              hipStream_t stream) {
  const float* input = (const float*)d_in[0];
  const float* bb_w  = (const float*)d_in[1];
  const float* bb_b  = (const float*)d_in[2];

  __hip_bfloat16* feats = (__hip_bfloat16*)d_ws;   // 2*32*768*768 bf16 = 75.5 MB
  float* out = (float*)d_out;

  const size_t PLANE = (size_t)2 * HWSZ;           // per-output-chunk for cout=2: 2*2*HW? no:
  // chunk sizes (elements): scores 2*2*HW, locations 2*2*HW, refinement 2*2*HW, fourier 2*20*HW
  const size_t SCORES_OFF = 0;
  const size_t LOC_OFF    = (size_t)2 * 2 * HWSZ;
  const size_t REF_OFF    = (size_t)2 * 2 * HWSZ * 2;
  const size_t FOUR_OFF   = (size_t)2 * 2 * HWSZ * 3;
  (void)PLANE; (void)out_size; (void)ws_size; (void)n_in; (void)in_sizes;

  backbone_kernel<<<4608, 256, 0, stream>>>(input, bb_w, bb_b, feats);

  const int HEAD_GRID = 2 * 48 * 48;               // 4608

  // score: k=3, cout=2
  head_kernel<3, 2, false><<<HEAD_GRID, 256, 0, stream>>>(
      feats,
      (const float*)d_in[3], (const float*)d_in[4], (const float*)d_in[5],
      (const float*)d_in[6], (const float*)d_in[7], (const float*)d_in[8],
      out + SCORES_OFF);

  // loc: k=7, cout=2
  head_kernel<7, 2, false><<<HEAD_GRID, 256, 0, stream>>>(
      feats,
      (const float*)d_in[9], (const float*)d_in[10], (const float*)d_in[11],
      (const float*)d_in[12], (const float*)d_in[13], (const float*)d_in[14],
      out + LOC_OFF);

  // four: k=7, cout=20
  head_kernel<7, 20, false><<<HEAD_GRID, 256, 0, stream>>>(
      feats,
      (const float*)d_in[15], (const float*)d_in[16], (const float*)d_in[17],
      (const float*)d_in[18], (const float*)d_in[19], (const float*)d_in[20],
      out + FOUR_OFF);

  // ref: k=7, cout=2, tanh*3
  head_kernel<7, 2, true><<<HEAD_GRID, 256, 0, stream>>>(
      feats,
      (const float*)d_in[21], (const float*)d_in[22], (const float*)d_in[23],
      (const float*)d_in[24], (const float*)d_in[25], (const float*)d_in[26],
      out + REF_OFF);
}

// Round 2
// 497.233 us; speedup vs baseline: 18.1745x; 18.1745x over previous
//
#include <hip/hip_runtime.h>
#include <hip/hip_bf16.h>
#include <cmath>

#define HH 768
#define WW 768
#define HWSZ (768*768)

typedef __attribute__((ext_vector_type(8))) short bhalf8;   // 8 bf16 in 4 VGPRs
typedef __attribute__((ext_vector_type(4))) float f32x4;

__device__ inline ushort f2bf(float f) {
  __hip_bfloat16 h = __float2bfloat16(f);
  return *reinterpret_cast<ushort*>(&h);
}

// ---------------- weight transform: w1[m][c][ky][kx] fp32 -> wT[pos][m][c] bf16 (s-folded),
// ---------------- bb[m] = b1[m]*s[m] + t[m]
__global__ __launch_bounds__(256) void wxform_kernel(
    const float* __restrict__ w1, const float* __restrict__ b1,
    const float* __restrict__ s,  const float* __restrict__ t,
    ushort* __restrict__ wT, float* __restrict__ bb, int npos)
{
  int i = blockIdx.x * 256 + threadIdx.x;
  if (i < npos * 1024) {
    int pos = i >> 10, mc = i & 1023, m = mc >> 5, c = mc & 31;
    wT[i] = f2bf(w1[(m * 32 + c) * npos + pos] * s[m]);
  }
  if (i < 32) bb[i] = b1[i] * s[i] + t[i];
}

// ---------------- backbone: conv3x3 (3->32) + bias + relu, feats[b][y][x][c] bf16 ----------------
__global__ __launch_bounds__(256) void backbone_kernel(
    const float* __restrict__ x, const float* __restrict__ w,
    const float* __restrict__ bias, ushort* __restrict__ feats)
{
  int p = blockIdx.x * 256 + threadIdx.x;          // 0 .. 2*HW-1
  int bb  = p / HWSZ;
  int rem = p - bb * HWSZ;
  int y   = rem / WW;
  int xx  = rem - y * WW;
  const float* xb = x + (size_t)bb * 3 * HWSZ;

  float v[3][3][3];
  #pragma unroll
  for (int c = 0; c < 3; c++)
    #pragma unroll
    for (int dy = 0; dy < 3; dy++)
      #pragma unroll
      for (int dx = 0; dx < 3; dx++) {
        int yy = y + dy - 1, xq = xx + dx - 1;
        v[c][dy][dx] = (yy >= 0 && yy < HH && xq >= 0 && xq < WW)
                         ? xb[(size_t)c * HWSZ + yy * WW + xq] : 0.f;
      }

  union { ushort u[32]; uint4 q[4]; } pk;
  #pragma unroll
  for (int o = 0; o < 32; o++) {
    float acc = bias[o];
    #pragma unroll
    for (int c = 0; c < 3; c++)
      #pragma unroll
      for (int dy = 0; dy < 3; dy++)
        #pragma unroll
        for (int dx = 0; dx < 3; dx++)
          acc = fmaf(w[((o * 3 + c) * 3 + dy) * 3 + dx], v[c][dy][dx], acc);
    pk.u[o] = f2bf(fmaxf(acc, 0.f));
  }
  uint4* dst = (uint4*)(feats + ((size_t)bb * HWSZ + rem) * 32);
  #pragma unroll
  for (int i = 0; i < 4; i++) dst[i] = pk.q[i];
}

// ---------------- MFMA head: conv KxK (32->32) -> BN(relu) -> conv1x1 ----------------
// GEMM: out[m][pix] = sum over (pos, c) of wT[pos][m][c] * tile[pix+pos][c]
template <int K, int COUT, bool DO_TANH>
__global__ __launch_bounds__(256) void head_mfma_kernel(
    const ushort* __restrict__ feats,       // [b][y][x][c] bf16
    const ushort* __restrict__ wT,          // [pos][m][c] bf16, s-folded
    const float*  __restrict__ bbias,       // [32] = b1*s + t
    const float*  __restrict__ w2, const float* __restrict__ b2,
    float* __restrict__ out)
{
  constexpr int PAD  = K / 2;
  constexpr int TW   = 16 + 2 * PAD;        // tile width with halo
  constexpr int NPIX = TW * TW;
  constexpr int CPAD = 40;                  // bf16 per pixel slot (80B, 16B-aligned)
  constexpr int SMEM_BYTES = (NPIX * CPAD * 2 > 256 * 33 * 4) ? NPIX * CPAD * 2
                                                              : 256 * 33 * 4;
  __shared__ __align__(16) char smem[SMEM_BYTES];
  ushort* tile = (ushort*)smem;

  int bx = blockIdx.x % 48;
  int by = (blockIdx.x / 48) % 48;
  int bb = blockIdx.x / (48 * 48);
  int x0 = bx * 16 - PAD, y0 = by * 16 - PAD;

  const ushort* fB = feats + (size_t)bb * HWSZ * 32;

  // ---- stage halo tile: all 32 channels per pixel (64B contiguous) ----
  for (int p = threadIdx.x; p < NPIX; p += 256) {
    int py = p / TW, px = p % TW;
    int yy = y0 + py, xx = x0 + px;
    uint4 q0 = {0,0,0,0}, q1 = {0,0,0,0}, q2 = {0,0,0,0}, q3 = {0,0,0,0};
    if (yy >= 0 && yy < HH && xx >= 0 && xx < WW) {
      const uint4* src = (const uint4*)(fB + ((size_t)yy * WW + xx) * 32);
      q0 = src[0]; q1 = src[1]; q2 = src[2]; q3 = src[3];
    }
    uint4* dst = (uint4*)(tile + (size_t)p * CPAD);
    dst[0] = q0; dst[1] = q1; dst[2] = q2; dst[3] = q3;
  }
  __syncthreads();

  int l  = threadIdx.x & 63;
  int wv = threadIdx.x >> 6;                // wave 0..3
  int px = l & 15;                          // pixel col / m row / out col
  int g  = l >> 4;                          // k-octet group

  f32x4 acc[2][4] = {};                     // [mid-half][pixel-row i]

  for (int ky = 0; ky < K; ky++) {
    bhalf8 areg[K][2];
    #pragma unroll
    for (int kx = 0; kx < K; kx++)
      #pragma unroll
      for (int mh = 0; mh < 2; mh++)
        areg[kx][mh] = *(const bhalf8*)(wT + (size_t)(ky * K + kx) * 1024
                                           + mh * 512 + px * 32 + g * 8);
    #pragma unroll
    for (int kx = 0; kx < K; kx++) {
      #pragma unroll
      for (int i = 0; i < 4; i++) {
        int pgrow = wv * 4 + i;             // output pixel row
        const bhalf8 bfrag = *(const bhalf8*)(
            tile + (size_t)((pgrow + ky) * TW + px + kx) * CPAD + g * 8);
        acc[0][i] = __builtin_amdgcn_mfma_f32_16x16x32_bf16(areg[kx][0], bfrag, acc[0][i], 0, 0, 0);
        acc[1][i] = __builtin_amdgcn_mfma_f32_16x16x32_bf16(areg[kx][1], bfrag, acc[1][i], 0, 0, 0);
      }
    }
  }

  // ---- BN + relu, write mids to LDS (pixel-major, pad 33) ----
  __syncthreads();
  float* mid = (float*)smem;
  #pragma unroll
  for (int mh = 0; mh < 2; mh++)
    #pragma unroll
    for (int i = 0; i < 4; i++) {
      int pgrow = wv * 4 + i;
      #pragma unroll
      for (int r = 0; r < 4; r++) {
        int m = mh * 16 + g * 4 + r;
        int pix = pgrow * 16 + px;
        mid[pix * 33 + m] = fmaxf(acc[mh][i][r] + bbias[m], 0.f);
      }
    }
  __syncthreads();

  // ---- 1x1 conv epilogue: one thread = one pixel ----
  int pix = threadIdx.x;
  int py  = pix >> 4, pxl = pix & 15;
  int oy  = by * 16 + py, ox = bx * 16 + pxl;
  size_t opix = (size_t)oy * WW + ox;
  float* ob = out + (size_t)bb * COUT * HWSZ;

  float m_[32];
  #pragma unroll
  for (int m = 0; m < 32; m++) m_[m] = mid[pix * 33 + m];

  #pragma unroll
  for (int oc = 0; oc < COUT; oc++) {
    float acc2 = b2[oc];
    #pragma unroll
    for (int m = 0; m < 32; m++) acc2 = fmaf(w2[oc * 32 + m], m_[m], acc2);
    if (DO_TANH) acc2 = tanhf(acc2) * 3.0f;
    ob[(size_t)oc * HWSZ + opix] = acc2;
  }
}

extern "C" void kernel_launch(void* const* d_in, const int* in_sizes, int n_in,
                              void* d_out, int out_size, void* d_ws, size_t ws_size,
                              hipStream_t stream) {
  const float* input = (const float*)d_in[0];
  const float* bb_w  = (const float*)d_in[1];
  const float* bb_b  = (const float*)d_in[2];

  // workspace layout
  ushort* feats = (ushort*)d_ws;                             // 2*HW*32 bf16 = 75.5 MB
  char* base = (char*)d_ws;
  const size_t FEATS_BYTES = (size_t)2 * HWSZ * 32 * 2;      // 75,497,472
  const size_t WT_STRIDE   = 49 * 1024 * 2;                  // 100,352 B per head
  ushort* wT0 = (ushort*)(base + FEATS_BYTES);
  float*  bb0 = (float*)(base + FEATS_BYTES + 4 * WT_STRIDE);
  (void)out_size; (void)ws_size; (void)n_in; (void)in_sizes;

  float* out = (float*)d_out;
  const size_t SCORES_OFF = 0;
  const size_t LOC_OFF    = (size_t)2 * 2 * HWSZ;
  const size_t REF_OFF    = (size_t)2 * 2 * HWSZ * 2;
  const size_t FOUR_OFF   = (size_t)2 * 2 * HWSZ * 3;

  // weight transforms (head order: score, loc, four, ref)
  const int npos_h[4] = {9, 49, 49, 49};
  for (int h = 0; h < 4; h++) {
    const float* w1 = (const float*)d_in[3 + h * 6 + 0];
    const float* b1 = (const float*)d_in[3 + h * 6 + 1];
    const float* s  = (const float*)d_in[3 + h * 6 + 2];
    const float* t  = (const float*)d_in[3 + h * 6 + 3];
    ushort* wT = (ushort*)((char*)wT0 + h * WT_STRIDE);
    float*  bbv = bb0 + h * 32;
    int n = npos_h[h] * 1024;
    wxform_kernel<<<(n + 255) / 256, 256, 0, stream>>>(w1, b1, s, t, wT, bbv, npos_h[h]);
  }

  backbone_kernel<<<4608, 256, 0, stream>>>(input, bb_w, bb_b, feats);

  const int HEAD_GRID = 2 * 48 * 48;                         // 4608

  // score: k=3, cout=2
  head_mfma_kernel<3, 2, false><<<HEAD_GRID, 256, 0, stream>>>(
      feats, (ushort*)((char*)wT0 + 0 * WT_STRIDE), bb0 + 0 * 32,
      (const float*)d_in[7], (const float*)d_in[8], out + SCORES_OFF);

  // loc: k=7, cout=2
  head_mfma_kernel<7, 2, false><<<HEAD_GRID, 256, 0, stream>>>(
      feats, (ushort*)((char*)wT0 + 1 * WT_STRIDE), bb0 + 1 * 32,
      (const float*)d_in[13], (const float*)d_in[14], out + LOC_OFF);

  // four: k=7, cout=20
  head_mfma_kernel<7, 20, false><<<HEAD_GRID, 256, 0, stream>>>(
      feats, (ushort*)((char*)wT0 + 2 * WT_STRIDE), bb0 + 2 * 32,
      (const float*)d_in[19], (const float*)d_in[20], out + FOUR_OFF);

  // ref: k=7, cout=2, tanh*3
  head_mfma_kernel<7, 2, true><<<HEAD_GRID, 256, 0, stream>>>(
      feats, (ushort*)((char*)wT0 + 3 * WT_STRIDE), bb0 + 3 * 32,
      (const float*)d_in[25], (const float*)d_in[26], out + REF_OFF);
}